// Round 8
// baseline (815.166 us; speedup 1.0000x reference)
//
#include <hip/hip_runtime.h>
#include <math.h>

typedef unsigned short u16;
typedef unsigned int u32;
typedef __attribute__((ext_vector_type(4))) unsigned short u16x4;
typedef __attribute__((ext_vector_type(8))) short bf16x8;
typedef __attribute__((ext_vector_type(4))) float f32x4;

#define B_ 4
#define S_ 2048
#define D_ 1024
#define H_ 16
#define NT (B_*S_)
#define DFF 4096

static __device__ __forceinline__ float bf2f(u16 u) {
    return __uint_as_float(((u32)u) << 16);
}
static __device__ __forceinline__ u16 f2bf(float f) {
    u32 u = __float_as_uint(f);
    u32 r = (u + 0x7fffu + ((u >> 16) & 1u)) >> 16;
    return (u16)r;
}
// async 16B/lane global->LDS (LDS dest = wave-uniform base + lane*16)
static __device__ __forceinline__ void gload_lds16(const void* g, void* l) {
    __builtin_amdgcn_global_load_lds(
        (const __attribute__((address_space(1))) void*)g,
        (__attribute__((address_space(3))) void*)l, 16, 0, 0);
}

// ------------------------------------------------- transpose fp32 -> bf16
__global__ void transpose_f2b4(const float* __restrict__ s0, const float* __restrict__ s1,
                               const float* __restrict__ s2, const float* __restrict__ s3,
                               u16* __restrict__ d0, u16* __restrict__ d1,
                               u16* __restrict__ d2, u16* __restrict__ d3,
                               int R, int C) {
    const float* in = s0; u16* out = d0;
    if (blockIdx.z == 1) { in = s1; out = d1; }
    else if (blockIdx.z == 2) { in = s2; out = d2; }
    else if (blockIdx.z == 3) { in = s3; out = d3; }
    __shared__ float t[32][33];
    int c0 = blockIdx.x * 32, r0 = blockIdx.y * 32;
    int x = threadIdx.x, y = threadIdx.y;
    #pragma unroll
    for (int i = 0; i < 4; i++)
        t[y + i*8][x] = in[(long)(r0 + y + i*8) * C + c0 + x];
    __syncthreads();
    #pragma unroll
    for (int i = 0; i < 4; i++)
        out[(long)(c0 + y + i*8) * R + r0 + x] = f2bf(t[x][y + i*8]);
}

__global__ void transpose_f2b(const float* __restrict__ in, u16* __restrict__ out,
                              int R, int C) {
    __shared__ float t[32][33];
    int c0 = blockIdx.x * 32, r0 = blockIdx.y * 32;
    int x = threadIdx.x, y = threadIdx.y;
    #pragma unroll
    for (int i = 0; i < 4; i++)
        t[y + i*8][x] = in[(long)(r0 + y + i*8) * C + c0 + x];
    __syncthreads();
    #pragma unroll
    for (int i = 0; i < 4; i++)
        out[(long)(c0 + y + i*8) * R + r0 + x] = f2bf(t[x][y + i*8]);
}

// V bf16 [B*S][D] -> Vt bf16 [B*H][64][S]. grid (S/32, 2, B*H), block (32,8)
__global__ void transpose_v(const u16* __restrict__ V, u16* __restrict__ Vt) {
    __shared__ u16 t[32][33];
    int z = blockIdx.z; int b = z >> 4, h = z & 15;
    int s0 = blockIdx.x * 32, d0 = blockIdx.y * 32;
    int x = threadIdx.x, y = threadIdx.y;
    const u16* in = V + ((long)b * S_ + s0) * D_ + h * 64 + d0;
    #pragma unroll
    for (int i = 0; i < 4; i++)
        t[y + i*8][x] = in[(long)(y + i*8) * D_ + x];
    __syncthreads();
    u16* out = Vt + ((long)z * 64 + d0) * S_ + s0;
    #pragma unroll
    for (int i = 0; i < 4; i++)
        out[(long)(y + i*8) * S_ + x] = t[x][y + i*8];
}

// ------------------------------------------------- mask -> additive bias (exp2 domain)
// mb[k] = mask ? -MMAX : -MMAX-10000   (MMAX=20 folded in)
__global__ void mask_bias_k(const int* __restrict__ am, float* __restrict__ mb) {
    int i = blockIdx.x * 256 + threadIdx.x;
    mb[i] = am[i] ? -20.0f : -10020.0f;
}

// ------------------------------------------------- layernorm (fp32 in, bf16 out)
__global__ __launch_bounds__(256) void ln_kernel(
    const float* __restrict__ X, const float* __restrict__ alpha,
    const float* __restrict__ beta, u16* __restrict__ Y) {
    int row = blockIdx.x, tid = threadIdx.x;
    float4 xv = ((const float4*)(X + (long)row * D_))[tid];
    float v[4] = {xv.x, xv.y, xv.z, xv.w};
    float s = 0.f, ss = 0.f;
    #pragma unroll
    for (int i = 0; i < 4; i++) { s += v[i]; ss += v[i]*v[i]; }
    #pragma unroll
    for (int off = 32; off >= 1; off >>= 1) {
        s += __shfl_xor(s, off);
        ss += __shfl_xor(ss, off);
    }
    __shared__ float red[8];
    __shared__ float stats[2];
    int w = tid >> 6;
    if ((tid & 63) == 0) { red[w] = s; red[4 + w] = ss; }
    __syncthreads();
    if (tid == 0) {
        float S = red[0] + red[1] + red[2] + red[3];
        float SS = red[4] + red[5] + red[6] + red[7];
        float mean = S * (1.f / D_);
        float var = SS * (1.f / D_) - mean * mean;
        stats[0] = mean; stats[1] = rsqrtf(var + 1e-5f);
    }
    __syncthreads();
    float mean = stats[0], rstd = stats[1];
    float4 av = ((const float4*)alpha)[tid];
    float4 bv = ((const float4*)beta)[tid];
    u16x4 o;
    o[0] = f2bf((v[0] - mean) * rstd * av.x + bv.x);
    o[1] = f2bf((v[1] - mean) * rstd * av.y + bv.y);
    o[2] = f2bf((v[2] - mean) * rstd * av.z + bv.z);
    o[3] = f2bf((v[3] - mean) * rstd * av.w + bv.w);
    *(u16x4*)(Y + (long)row * D_ + tid * 4) = o;
}

// ------------------------------------------------- GEMM (bf16 A, bf16 B^T)
#define BM 128
#define BN 128
#define BK 64

__global__ __launch_bounds__(256, 2) void gemm_bt(
    const u16* __restrict__ A,
    const u16* __restrict__ Bt0, const u16* __restrict__ Bt1, const u16* __restrict__ Bt2,
    void* __restrict__ C0, void* __restrict__ C1, void* __restrict__ C2,
    int M, int N, int K, int mode,
    const float* __restrict__ bias, const float* __restrict__ resid) {
    const u16* Bt = Bt0; void* C = C0;
    if (blockIdx.z == 1) { Bt = Bt1; C = C1; }
    else if (blockIdx.z == 2) { Bt = Bt2; C = C2; }

    __shared__ __align__(16) u16 Asm[BM * BK];
    __shared__ __align__(16) u16 Bsm[BN * BK];

    int tid = threadIdx.x;
    int lane = tid & 63, wave = tid >> 6;
    int l15 = lane & 15, quad = lane >> 4;
    int wm = wave & 1, wn = wave >> 1;
    long tm0 = (long)blockIdx.y * BM, tn0 = (long)blockIdx.x * BN;

    int srow = lane >> 3;
    int scol = (lane & 7) * 8;

    f32x4 acc[4][4] = {};

    for (int k0 = 0; k0 < K; k0 += BK) {
        __syncthreads();
        #pragma unroll
        for (int c = 0; c < 4; c++) {
            int chunk = wave * 4 + c;
            int row = chunk * 8 + srow;
            gload_lds16(&A[(tm0 + row) * (long)K + k0 + scol], &Asm[chunk * 512]);
            gload_lds16(&Bt[(tn0 + row) * (long)K + k0 + scol], &Bsm[chunk * 512]);
        }
        __syncthreads();
        #pragma unroll
        for (int ks = 0; ks < 2; ks++) {
            bf16x8 af[4], bfm[4];
            #pragma unroll
            for (int mt = 0; mt < 4; mt++)
                af[mt] = *(const bf16x8*)&Asm[(wm*64 + mt*16 + l15) * BK + ks*32 + quad*8];
            #pragma unroll
            for (int nt = 0; nt < 4; nt++)
                bfm[nt] = *(const bf16x8*)&Bsm[(wn*64 + nt*16 + l15) * BK + ks*32 + quad*8];
            #pragma unroll
            for (int mt = 0; mt < 4; mt++)
                #pragma unroll
                for (int nt = 0; nt < 4; nt++)
                    acc[mt][nt] = __builtin_amdgcn_mfma_f32_16x16x32_bf16(
                        af[mt], bfm[nt], acc[mt][nt], 0, 0, 0);
        }
    }

    #pragma unroll
    for (int mt = 0; mt < 4; mt++) {
        #pragma unroll
        for (int nt = 0; nt < 4; nt++) {
            #pragma unroll
            for (int i = 0; i < 4; i++) {
                long r = tm0 + wm*64 + mt*16 + quad*4 + i;
                long cn = tn0 + wn*64 + nt*16 + l15;
                long idx = r * N + cn;
                float val = acc[mt][nt][i];
                if (mode == 0) {
                    ((u16*)C)[idx] = f2bf(val);
                } else if (mode == 1) {
                    ((float*)C)[idx] = val + resid[idx];
                } else if (mode == 2) {
                    val += bias[cn];
                    val = 0.5f * val * (1.0f + erff(val * 0.70710678118654752f));
                    ((u16*)C)[idx] = f2bf(val);
                } else {
                    ((float*)C)[idx] = val + bias[cn] + resid[idx];
                }
            }
        }
    }
}

// ------------------------------------------------- attention
// R6 shape (32-q-tile x 64-k-tile, wave-autonomous, zero barriers, grid
// (bh=64, 8): head-per-XCD L2 locality + paired tiles j/63-j for balance)
// + register double-buffered K/V/mask prefetch (hides L2 latency)
// + mask folded into additive exp2-bias (no compares in main loop)
// + causal predication only in the diagonal remainder tile
// + S^T layout: P round-trip = 8x ds_write_b64 + 4x ds_read_b128.
#define LDP 72   // P row stride in u16

__global__ __launch_bounds__(256, 2) void attn_kernel(
    const u16* __restrict__ Q, const u16* __restrict__ Kg, const u16* __restrict__ Vt,
    const float* __restrict__ maskb, u16* __restrict__ O) {
    __shared__ __align__(16) u16 Psm[4][32 * LDP];
    int tid = threadIdx.x;
    int lane = tid & 63, wave = tid >> 6;
    int l15 = lane & 15, quad = lane >> 4;
    int bh = blockIdx.x; int b = bh >> 4, h = bh & 15;
    int j = wave * 8 + blockIdx.y;     // 0..31
    long tokBase = (long)b * S_;
    const float SCL = 0.125f * 1.4426950408889634f;  // exp2 domain

    const bf16x8 ones = {16256,16256,16256,16256,16256,16256,16256,16256}; // bf16 1.0
    u16* Pw = Psm[wave];
    const float* mbias_b = maskb + b * S_;
    const u16* Kbase = Kg + (tokBase + l15) * D_ + h * 64;
    const u16* Vbase = Vt + ((long)bh * 64 + l15) * S_;

    #pragma unroll
    for (int half = 0; half < 2; half++) {
        int t = half ? (63 - j) : j;   // q-tile 0..63 (32 rows)
        int q0 = t * 32;
        int nf = t >> 1;               // full (non-causal) 64-wide k-tiles
        int r0 = nf * 64;              // remainder tile start
        bool todd = (t & 1) != 0;
        int qg0 = q0 + l15, qg1 = q0 + 16 + l15;

        bf16x8 aq[2][2];
        #pragma unroll
        for (int qh = 0; qh < 2; qh++) {
            const u16* qptr = Q + (tokBase + q0 + qh*16 + l15) * D_ + h * 64;
            aq[qh][0] = *(const bf16x8*)(qptr + quad * 8);
            aq[qh][1] = *(const bf16x8*)(qptr + 32 + quad * 8);
        }

        f32x4 o[2][4] = {};
        f32x4 lacc[2] = {};

        bf16x8 ka[4][2], va[4][2], kb2[4][2], vb2[4][2];
        float4 ma[4], mb2[4];

        auto load_kv = [&](bf16x8 (&KB)[4][2], bf16x8 (&VB)[4][2],
                           float4 (&MB)[4], int K0) {
            #pragma unroll
            for (int st = 0; st < 4; st++) {
                const u16* kp = Kbase + (long)(K0 + st*16) * D_;
                KB[st][0] = *(const bf16x8*)(kp + quad * 8);
                KB[st][1] = *(const bf16x8*)(kp + 32 + quad * 8);
                MB[st] = *(const float4*)&mbias_b[K0 + st*16 + quad*4];
            }
            #pragma unroll
            for (int dt = 0; dt < 4; dt++) {
                const u16* vp = Vbase + (long)(dt*16) * S_ + K0;
                VB[dt][0] = *(const bf16x8*)(vp + quad * 8);
                VB[dt][1] = *(const bf16x8*)(vp + 32 + quad * 8);
            }
        };

        auto pv_accum = [&](bf16x8 (&VB)[4][2]) {
            asm volatile("s_waitcnt lgkmcnt(0)" ::: "memory");
            #pragma unroll
            for (int qh = 0; qh < 2; qh++) {
                bf16x8 ap0 = *(const bf16x8*)&Pw[(qh*16 + l15) * LDP + quad*8];
                bf16x8 ap1 = *(const bf16x8*)&Pw[(qh*16 + l15) * LDP + 32 + quad*8];
                #pragma unroll
                for (int dt = 0; dt < 4; dt++) {
                    o[qh][dt] = __builtin_amdgcn_mfma_f32_16x16x32_bf16(ap0, VB[dt][0], o[qh][dt], 0,0,0);
                    o[qh][dt] = __builtin_amdgcn_mfma_f32_16x16x32_bf16(ap1, VB[dt][1], o[qh][dt], 0,0,0);
                }
                lacc[qh] = __builtin_amdgcn_mfma_f32_16x16x32_bf16(ap0, ones, lacc[qh], 0,0,0);
                lacc[qh] = __builtin_amdgcn_mfma_f32_16x16x32_bf16(ap1, ones, lacc[qh], 0,0,0);
            }
        };

        auto compute_full = [&](bf16x8 (&KB)[4][2], bf16x8 (&VB)[4][2],
                                float4 (&MB)[4]) {
            f32x4 s[2][4] = {};
            #pragma unroll
            for (int st = 0; st < 4; st++) {
                #pragma unroll
                for (int qh = 0; qh < 2; qh++) {
                    s[qh][st] = __builtin_amdgcn_mfma_f32_16x16x32_bf16(KB[st][0], aq[qh][0], s[qh][st], 0,0,0);
                    s[qh][st] = __builtin_amdgcn_mfma_f32_16x16x32_bf16(KB[st][1], aq[qh][1], s[qh][st], 0,0,0);
                }
            }
            #pragma unroll
            for (int st = 0; st < 4; st++) {
                #pragma unroll
                for (int qh = 0; qh < 2; qh++) {
                    float p0 = __builtin_amdgcn_exp2f(fmaf(s[qh][st][0], SCL, MB[st].x));
                    float p1 = __builtin_amdgcn_exp2f(fmaf(s[qh][st][1], SCL, MB[st].y));
                    float p2 = __builtin_amdgcn_exp2f(fmaf(s[qh][st][2], SCL, MB[st].z));
                    float p3 = __builtin_amdgcn_exp2f(fmaf(s[qh][st][3], SCL, MB[st].w));
                    u32 pk0 = __builtin_amdgcn_perm(__float_as_uint(p1), __float_as_uint(p0), 0x07060302u);
                    u32 pk1 = __builtin_amdgcn_perm(__float_as_uint(p3), __float_as_uint(p2), 0x07060302u);
                    uint2 wv = {pk0, pk1};
                    *(uint2*)&Pw[(qh*16 + l15) * LDP + st*16 + quad*4] = wv;
                }
            }
            pv_accum(VB);
        };

        auto compute_rem = [&](bf16x8 (&KB)[4][2], bf16x8 (&VB)[4][2],
                               float4 (&MB)[4]) {
            // st 0,1 always; st 2,3 only when t odd. Diagonal (causal) blocks:
            // t even -> st 0,1 ; t odd -> st 2,3.
            f32x4 s[2][4] = {};
            int nst = todd ? 4 : 2;
            for (int st = 0; st < nst; st++) {
                #pragma unroll
                for (int qh = 0; qh < 2; qh++) {
                    s[qh][st] = __builtin_amdgcn_mfma_f32_16x16x32_bf16(KB[st][0], aq[qh][0], s[qh][st], 0,0,0);
                    s[qh][st] = __builtin_amdgcn_mfma_f32_16x16x32_bf16(KB[st][1], aq[qh][1], s[qh][st], 0,0,0);
                }
            }
            for (int st = 0; st < nst; st++) {
                bool causal = todd ? (st >= 2) : true;
                int kbq = r0 + st*16 + quad*4;
                #pragma unroll
                for (int qh = 0; qh < 2; qh++) {
                    int qg = qh ? qg1 : qg0;
                    float p0 = __builtin_amdgcn_exp2f(fmaf(s[qh][st][0], SCL, MB[st].x));
                    float p1 = __builtin_amdgcn_exp2f(fmaf(s[qh][st][1], SCL, MB[st].y));
                    float p2 = __builtin_amdgcn_exp2f(fmaf(s[qh][st][2], SCL, MB[st].z));
                    float p3 = __builtin_amdgcn_exp2f(fmaf(s[qh][st][3], SCL, MB[st].w));
                    if (causal) {
                        p0 = (kbq + 0 <= qg) ? p0 : 0.f;
                        p1 = (kbq + 1 <= qg) ? p1 : 0.f;
                        p2 = (kbq + 2 <= qg) ? p2 : 0.f;
                        p3 = (kbq + 3 <= qg) ? p3 : 0.f;
                    }
                    u32 pk0 = __builtin_amdgcn_perm(__float_as_uint(p1), __float_as_uint(p0), 0x07060302u);
                    u32 pk1 = __builtin_amdgcn_perm(__float_as_uint(p3), __float_as_uint(p2), 0x07060302u);
                    uint2 wv = {pk0, pk1};
                    *(uint2*)&Pw[(qh*16 + l15) * LDP + st*16 + quad*4] = wv;
                }
            }
            if (!todd) {
                uint2 z2 = {0u, 0u};
                #pragma unroll
                for (int st = 2; st < 4; st++)
                    #pragma unroll
                    for (int qh = 0; qh < 2; qh++)
                        *(uint2*)&Pw[(qh*16 + l15) * LDP + st*16 + quad*4] = z2;
            }
            pv_accum(VB);
        };

        // software-pipelined k-loop: tiles 0..nf (tile nf = remainder)
        load_kv(ka, va, ma, 0);
        for (int kt = 0; kt < nf; kt += 2) {
            load_kv(kb2, vb2, mb2, (kt + 1) * 64);
            compute_full(ka, va, ma);
            if (kt + 1 < nf) {
                load_kv(ka, va, ma, (kt + 2) * 64);
                compute_full(kb2, vb2, mb2);
            }
        }
        if (nf & 1) compute_rem(kb2, vb2, mb2);
        else        compute_rem(ka, va, ma);

        #pragma unroll
        for (int qh = 0; qh < 2; qh++) {
            #pragma unroll
            for (int i = 0; i < 4; i++) {
                float inv = 1.f / lacc[qh][i];
                long r = tokBase + q0 + qh*16 + quad*4 + i;
                #pragma unroll
                for (int dt = 0; dt < 4; dt++)
                    O[r * D_ + h*64 + dt*16 + l15] = f2bf(o[qh][dt][i] * inv);
            }
        }
    }
}

// ------------------------------------------------- launch
extern "C" void kernel_launch(void* const* d_in, const int* in_sizes, int n_in,
                              void* d_out, int out_size, void* d_ws, size_t ws_size,
                              hipStream_t stream) {
    const float* x    = (const float*)d_in[0];
    const int*   am   = (const int*)d_in[1];
    const float* ln1a = (const float*)d_in[2];
    const float* ln1b = (const float*)d_in[3];
    const float* ln2a = (const float*)d_in[4];
    const float* ln2b = (const float*)d_in[5];
    const float* wq   = (const float*)d_in[6];
    const float* wk   = (const float*)d_in[7];
    const float* wv   = (const float*)d_in[8];
    const float* wo   = (const float*)d_in[9];
    const float* w1   = (const float*)d_in[10];
    const float* b1   = (const float*)d_in[11];
    const float* w2   = (const float*)d_in[12];
    const float* b2   = (const float*)d_in[13];
    float* out = (float*)d_out;

    // Workspace: 72 MB, liveness-overlapped 16MB slots.
    char* ws = (char*)d_ws;
    const size_t MB16 = (size_t)16 * 1024 * 1024;
    u16* y1      = (u16*)(ws + 0 * MB16);
    u16* q       = (u16*)(ws + 1 * MB16);
    u16* k       = (u16*)(ws + 2 * MB16);
    u16* v       = (u16*)(ws + 3 * MB16);
    u16* wqt     = (u16*)(ws + 4 * MB16 + 0 * (size_t)D_ * D_ * 2);
    u16* wkt     = (u16*)(ws + 4 * MB16 + 1 * (size_t)D_ * D_ * 2);
    u16* wvt     = (u16*)(ws + 4 * MB16 + 2 * (size_t)D_ * D_ * 2);
    u16* wot     = (u16*)(ws + 4 * MB16 + 3 * (size_t)D_ * D_ * 2);
    u16* y2      = y1;
    u16* w1t     = q;
    u16* w2t     = q + (size_t)D_ * DFF;
    u16* h_full  = k;
    u16* ctx     = v;
    u16*   vt  = (u16*)d_out;                             // [0,16MB) of d_out
    float* mbias = (float*)((char*)d_out + 24 * 1024 * 1024); // 32KB scratch, dead before x1f
    float* x1f = out;

    dim3 tb(32, 8);
    transpose_f2b4<<<dim3(D_/32, D_/32, 4), tb, 0, stream>>>(
        wq, wk, wv, wo, wqt, wkt, wvt, wot, D_, D_);

    ln_kernel<<<NT, 256, 0, stream>>>(x, ln1a, ln1b, y1);

    gemm_bt<<<dim3(D_/BN, NT/BM, 3), 256, 0, stream>>>(
        y1, wqt, wkt, wvt, q, k, v, NT, D_, D_, 0, nullptr, nullptr);

    transpose_v<<<dim3(S_/32, 2, B_*H_), tb, 0, stream>>>(v, vt);
    mask_bias_k<<<dim3(NT/256), 256, 0, stream>>>(am, mbias);

    attn_kernel<<<dim3(B_*H_, 8), 256, 0, stream>>>(q, k, vt, mbias, ctx);

    gemm_bt<<<dim3(D_/BN, NT/BM, 1), 256, 0, stream>>>(
        ctx, wot, wot, wot, x1f, x1f, x1f, NT, D_, D_, 1, nullptr, x);

    transpose_f2b<<<dim3(DFF/32, D_/32), tb, 0, stream>>>(w1, w1t, D_, DFF);
    transpose_f2b<<<dim3(D_/32, DFF/32), tb, 0, stream>>>(w2, w2t, DFF, D_);

    ln_kernel<<<NT, 256, 0, stream>>>(x1f, ln2a, ln2b, y2);

    gemm_bt<<<dim3(DFF/BN, NT/BM, 1), 256, 0, stream>>>(
        y2, w1t, w1t, w1t, h_full, h_full, h_full, NT, DFF, D_, 2, b1, nullptr);
    gemm_bt<<<dim3(D_/BN, NT/BM, 1), 256, 0, stream>>>(
        h_full, w2t, w2t, w2t, out, out, out, NT, D_, DFF, 3, b2, x1f);
}

// Round 9
// 778.040 us; speedup vs baseline: 1.0477x; 1.0477x over previous
//
#include <hip/hip_runtime.h>
#include <math.h>

typedef unsigned short u16;
typedef unsigned int u32;
typedef __attribute__((ext_vector_type(4))) unsigned short u16x4;
typedef __attribute__((ext_vector_type(8))) short bf16x8;
typedef __attribute__((ext_vector_type(4))) float f32x4;

#define B_ 4
#define S_ 2048
#define D_ 1024
#define H_ 16
#define NT (B_*S_)
#define DFF 4096

static __device__ __forceinline__ float bf2f(u16 u) {
    return __uint_as_float(((u32)u) << 16);
}
static __device__ __forceinline__ u16 f2bf(float f) {
    u32 u = __float_as_uint(f);
    u32 r = (u + 0x7fffu + ((u >> 16) & 1u)) >> 16;
    return (u16)r;
}
// async 16B/lane global->LDS (LDS dest = wave-uniform base + lane*16)
static __device__ __forceinline__ void gload_lds16(const void* g, void* l) {
    __builtin_amdgcn_global_load_lds(
        (const __attribute__((address_space(1))) void*)g,
        (__attribute__((address_space(3))) void*)l, 16, 0, 0);
}

// ------------------------------------------------- transpose fp32 -> bf16
__global__ void transpose_f2b4(const float* __restrict__ s0, const float* __restrict__ s1,
                               const float* __restrict__ s2, const float* __restrict__ s3,
                               u16* __restrict__ d0, u16* __restrict__ d1,
                               u16* __restrict__ d2, u16* __restrict__ d3,
                               int R, int C) {
    const float* in = s0; u16* out = d0;
    if (blockIdx.z == 1) { in = s1; out = d1; }
    else if (blockIdx.z == 2) { in = s2; out = d2; }
    else if (blockIdx.z == 3) { in = s3; out = d3; }
    __shared__ float t[32][33];
    int c0 = blockIdx.x * 32, r0 = blockIdx.y * 32;
    int x = threadIdx.x, y = threadIdx.y;
    #pragma unroll
    for (int i = 0; i < 4; i++)
        t[y + i*8][x] = in[(long)(r0 + y + i*8) * C + c0 + x];
    __syncthreads();
    #pragma unroll
    for (int i = 0; i < 4; i++)
        out[(long)(c0 + y + i*8) * R + r0 + x] = f2bf(t[x][y + i*8]);
}

__global__ void transpose_f2b(const float* __restrict__ in, u16* __restrict__ out,
                              int R, int C) {
    __shared__ float t[32][33];
    int c0 = blockIdx.x * 32, r0 = blockIdx.y * 32;
    int x = threadIdx.x, y = threadIdx.y;
    #pragma unroll
    for (int i = 0; i < 4; i++)
        t[y + i*8][x] = in[(long)(r0 + y + i*8) * C + c0 + x];
    __syncthreads();
    #pragma unroll
    for (int i = 0; i < 4; i++)
        out[(long)(c0 + y + i*8) * R + r0 + x] = f2bf(t[x][y + i*8]);
}

// V bf16 [B*S][D] -> Vt bf16 [B*H][64][S]. grid (S/32, 2, B*H), block (32,8)
__global__ void transpose_v(const u16* __restrict__ V, u16* __restrict__ Vt) {
    __shared__ u16 t[32][33];
    int z = blockIdx.z; int b = z >> 4, h = z & 15;
    int s0 = blockIdx.x * 32, d0 = blockIdx.y * 32;
    int x = threadIdx.x, y = threadIdx.y;
    const u16* in = V + ((long)b * S_ + s0) * D_ + h * 64 + d0;
    #pragma unroll
    for (int i = 0; i < 4; i++)
        t[y + i*8][x] = in[(long)(y + i*8) * D_ + x];
    __syncthreads();
    u16* out = Vt + ((long)z * 64 + d0) * S_ + s0;
    #pragma unroll
    for (int i = 0; i < 4; i++)
        out[(long)(y + i*8) * S_ + x] = t[x][y + i*8];
}

// ------------------------------------------------- mask -> additive bias (exp2 domain)
__global__ void mask_bias_k(const int* __restrict__ am, float* __restrict__ mb) {
    int i = blockIdx.x * 256 + threadIdx.x;
    mb[i] = am[i] ? -20.0f : -10020.0f;
}

// ------------------------------------------------- layernorm (fp32 in, bf16 out)
__global__ __launch_bounds__(256) void ln_kernel(
    const float* __restrict__ X, const float* __restrict__ alpha,
    const float* __restrict__ beta, u16* __restrict__ Y) {
    int row = blockIdx.x, tid = threadIdx.x;
    float4 xv = ((const float4*)(X + (long)row * D_))[tid];
    float v[4] = {xv.x, xv.y, xv.z, xv.w};
    float s = 0.f, ss = 0.f;
    #pragma unroll
    for (int i = 0; i < 4; i++) { s += v[i]; ss += v[i]*v[i]; }
    #pragma unroll
    for (int off = 32; off >= 1; off >>= 1) {
        s += __shfl_xor(s, off);
        ss += __shfl_xor(ss, off);
    }
    __shared__ float red[8];
    __shared__ float stats[2];
    int w = tid >> 6;
    if ((tid & 63) == 0) { red[w] = s; red[4 + w] = ss; }
    __syncthreads();
    if (tid == 0) {
        float S = red[0] + red[1] + red[2] + red[3];
        float SS = red[4] + red[5] + red[6] + red[7];
        float mean = S * (1.f / D_);
        float var = SS * (1.f / D_) - mean * mean;
        stats[0] = mean; stats[1] = rsqrtf(var + 1e-5f);
    }
    __syncthreads();
    float mean = stats[0], rstd = stats[1];
    float4 av = ((const float4*)alpha)[tid];
    float4 bv = ((const float4*)beta)[tid];
    u16x4 o;
    o[0] = f2bf((v[0] - mean) * rstd * av.x + bv.x);
    o[1] = f2bf((v[1] - mean) * rstd * av.y + bv.y);
    o[2] = f2bf((v[2] - mean) * rstd * av.z + bv.z);
    o[3] = f2bf((v[3] - mean) * rstd * av.w + bv.w);
    *(u16x4*)(Y + (long)row * D_ + tid * 4) = o;
}

// ------------------------------------------------- GEMM (bf16 A, bf16 B^T)
#define BM 128
#define BN 128
#define BK 64

__global__ __launch_bounds__(256, 2) void gemm_bt(
    const u16* __restrict__ A,
    const u16* __restrict__ Bt0, const u16* __restrict__ Bt1, const u16* __restrict__ Bt2,
    void* __restrict__ C0, void* __restrict__ C1, void* __restrict__ C2,
    int M, int N, int K, int mode,
    const float* __restrict__ bias, const float* __restrict__ resid) {
    const u16* Bt = Bt0; void* C = C0;
    if (blockIdx.z == 1) { Bt = Bt1; C = C1; }
    else if (blockIdx.z == 2) { Bt = Bt2; C = C2; }

    __shared__ __align__(16) u16 Asm[BM * BK];
    __shared__ __align__(16) u16 Bsm[BN * BK];

    int tid = threadIdx.x;
    int lane = tid & 63, wave = tid >> 6;
    int l15 = lane & 15, quad = lane >> 4;
    int wm = wave & 1, wn = wave >> 1;
    long tm0 = (long)blockIdx.y * BM, tn0 = (long)blockIdx.x * BN;

    int srow = lane >> 3;
    int scol = (lane & 7) * 8;

    f32x4 acc[4][4] = {};

    for (int k0 = 0; k0 < K; k0 += BK) {
        __syncthreads();
        #pragma unroll
        for (int c = 0; c < 4; c++) {
            int chunk = wave * 4 + c;
            int row = chunk * 8 + srow;
            gload_lds16(&A[(tm0 + row) * (long)K + k0 + scol], &Asm[chunk * 512]);
            gload_lds16(&Bt[(tn0 + row) * (long)K + k0 + scol], &Bsm[chunk * 512]);
        }
        __syncthreads();
        #pragma unroll
        for (int ks = 0; ks < 2; ks++) {
            bf16x8 af[4], bfm[4];
            #pragma unroll
            for (int mt = 0; mt < 4; mt++)
                af[mt] = *(const bf16x8*)&Asm[(wm*64 + mt*16 + l15) * BK + ks*32 + quad*8];
            #pragma unroll
            for (int nt = 0; nt < 4; nt++)
                bfm[nt] = *(const bf16x8*)&Bsm[(wn*64 + nt*16 + l15) * BK + ks*32 + quad*8];
            #pragma unroll
            for (int mt = 0; mt < 4; mt++)
                #pragma unroll
                for (int nt = 0; nt < 4; nt++)
                    acc[mt][nt] = __builtin_amdgcn_mfma_f32_16x16x32_bf16(
                        af[mt], bfm[nt], acc[mt][nt], 0, 0, 0);
        }
    }

    #pragma unroll
    for (int mt = 0; mt < 4; mt++) {
        #pragma unroll
        for (int nt = 0; nt < 4; nt++) {
            #pragma unroll
            for (int i = 0; i < 4; i++) {
                long r = tm0 + wm*64 + mt*16 + quad*4 + i;
                long cn = tn0 + wn*64 + nt*16 + l15;
                long idx = r * N + cn;
                float val = acc[mt][nt][i];
                if (mode == 0) {
                    ((u16*)C)[idx] = f2bf(val);
                } else if (mode == 1) {
                    ((float*)C)[idx] = val + resid[idx];
                } else if (mode == 2) {
                    val += bias[cn];
                    val = 0.5f * val * (1.0f + erff(val * 0.70710678118654752f));
                    ((u16*)C)[idx] = f2bf(val);
                } else {
                    ((float*)C)[idx] = val + bias[cn] + resid[idx];
                }
            }
        }
    }
}

// ------------------------------------------------- attention
// R6 shape: one wave = 32-q-tile, 64-k-tiles, single-buffered register loads,
// zero barriers. Grid (bh=64, 8): head-per-XCD L2 locality; paired tiles
// j/63-j for perfect balance. VALU diet vs R6:
//  - S^T scores (swapped MFMA operands) -> P round-trip is 8x ds_write_b64 +
//    4x ds_read_b128 (not 32 scalar writes); truncating bf16 pack (1 v_perm).
//  - mask folded into additive exp2-bias (no compares in full tiles).
//  - causal predication only in the diagonal remainder tile.
// NO register double-buffering (R8 post-mortem: it spills -> 330MB scratch).
#define LDP 72   // P row stride in u16

__global__ __launch_bounds__(256, 2) void attn_kernel(
    const u16* __restrict__ Q, const u16* __restrict__ Kg, const u16* __restrict__ Vt,
    const float* __restrict__ maskb, u16* __restrict__ O) {
    __shared__ __align__(16) u16 Psm[4][32 * LDP];
    int tid = threadIdx.x;
    int lane = tid & 63, wave = tid >> 6;
    int l15 = lane & 15, quad = lane >> 4;
    int bh = blockIdx.x; int b = bh >> 4, h = bh & 15;
    int j = wave * 8 + blockIdx.y;     // 0..31
    long tokBase = (long)b * S_;
    const float SCL = 0.125f * 1.4426950408889634f;  // exp2 domain

    const bf16x8 ones = {16256,16256,16256,16256,16256,16256,16256,16256}; // bf16 1.0
    u16* Pw = Psm[wave];
    const float* mbias_b = maskb + b * S_;
    const u16* Kbase = Kg + (tokBase + l15) * D_ + h * 64;
    const u16* Vbase = Vt + ((long)bh * 64 + l15) * S_;

    #pragma unroll
    for (int half = 0; half < 2; half++) {
        int t = half ? (63 - j) : j;   // q-tile 0..63 (32 rows)
        int q0 = t * 32;
        int nf = t >> 1;               // number of full (non-causal) 64-wide tiles
        int r0 = nf * 64;              // remainder tile start
        bool todd = (t & 1) != 0;
        int qg0 = q0 + l15, qg1 = q0 + 16 + l15;

        bf16x8 aq[2][2];
        #pragma unroll
        for (int qh = 0; qh < 2; qh++) {
            const u16* qptr = Q + (tokBase + q0 + qh*16 + l15) * D_ + h * 64;
            aq[qh][0] = *(const bf16x8*)(qptr + quad * 8);
            aq[qh][1] = *(const bf16x8*)(qptr + 32 + quad * 8);
        }

        f32x4 o[2][4] = {};
        f32x4 lacc[2] = {};

        // ---- full tiles (no causal, no mask compares) ----
        for (int kt = 0; kt < nf; kt++) {
            int k0 = kt * 64;
            bf16x8 kb[4][2], vb[4][2];
            float4 mf[4];
            #pragma unroll
            for (int st = 0; st < 4; st++) {
                const u16* kp = Kbase + (long)(k0 + st*16) * D_;
                kb[st][0] = *(const bf16x8*)(kp + quad * 8);
                kb[st][1] = *(const bf16x8*)(kp + 32 + quad * 8);
                mf[st] = *(const float4*)&mbias_b[k0 + st*16 + quad*4];
            }
            #pragma unroll
            for (int dt = 0; dt < 4; dt++) {
                const u16* vp = Vbase + (long)(dt*16) * S_ + k0;
                vb[dt][0] = *(const bf16x8*)(vp + quad * 8);
                vb[dt][1] = *(const bf16x8*)(vp + 32 + quad * 8);
            }

            f32x4 s[2][4] = {};
            #pragma unroll
            for (int st = 0; st < 4; st++) {
                #pragma unroll
                for (int qh = 0; qh < 2; qh++) {
                    s[qh][st] = __builtin_amdgcn_mfma_f32_16x16x32_bf16(kb[st][0], aq[qh][0], s[qh][st], 0,0,0);
                    s[qh][st] = __builtin_amdgcn_mfma_f32_16x16x32_bf16(kb[st][1], aq[qh][1], s[qh][st], 0,0,0);
                }
            }
            #pragma unroll
            for (int st = 0; st < 4; st++) {
                #pragma unroll
                for (int qh = 0; qh < 2; qh++) {
                    float p0 = __builtin_amdgcn_exp2f(fmaf(s[qh][st][0], SCL, mf[st].x));
                    float p1 = __builtin_amdgcn_exp2f(fmaf(s[qh][st][1], SCL, mf[st].y));
                    float p2 = __builtin_amdgcn_exp2f(fmaf(s[qh][st][2], SCL, mf[st].z));
                    float p3 = __builtin_amdgcn_exp2f(fmaf(s[qh][st][3], SCL, mf[st].w));
                    u32 pk0 = __builtin_amdgcn_perm(__float_as_uint(p1), __float_as_uint(p0), 0x07060302u);
                    u32 pk1 = __builtin_amdgcn_perm(__float_as_uint(p3), __float_as_uint(p2), 0x07060302u);
                    uint2 wv = {pk0, pk1};
                    *(uint2*)&Pw[(qh*16 + l15) * LDP + st*16 + quad*4] = wv;
                }
            }
            asm volatile("s_waitcnt lgkmcnt(0)" ::: "memory");
            #pragma unroll
            for (int qh = 0; qh < 2; qh++) {
                bf16x8 ap0 = *(const bf16x8*)&Pw[(qh*16 + l15) * LDP + quad*8];
                bf16x8 ap1 = *(const bf16x8*)&Pw[(qh*16 + l15) * LDP + 32 + quad*8];
                #pragma unroll
                for (int dt = 0; dt < 4; dt++) {
                    o[qh][dt] = __builtin_amdgcn_mfma_f32_16x16x32_bf16(ap0, vb[dt][0], o[qh][dt], 0,0,0);
                    o[qh][dt] = __builtin_amdgcn_mfma_f32_16x16x32_bf16(ap1, vb[dt][1], o[qh][dt], 0,0,0);
                }
                lacc[qh] = __builtin_amdgcn_mfma_f32_16x16x32_bf16(ap0, ones, lacc[qh], 0,0,0);
                lacc[qh] = __builtin_amdgcn_mfma_f32_16x16x32_bf16(ap1, ones, lacc[qh], 0,0,0);
            }
        }

        // ---- remainder tile at r0 (diagonal) ----
        {
            bf16x8 kb[4][2], vb[4][2];
            float4 mf[4];
            int nst = todd ? 4 : 2;
            for (int st = 0; st < nst; st++) {
                const u16* kp = Kbase + (long)(r0 + st*16) * D_;
                kb[st][0] = *(const bf16x8*)(kp + quad * 8);
                kb[st][1] = *(const bf16x8*)(kp + 32 + quad * 8);
                mf[st] = *(const float4*)&mbias_b[r0 + st*16 + quad*4];
            }
            #pragma unroll
            for (int dt = 0; dt < 4; dt++) {
                const u16* vp = Vbase + (long)(dt*16) * S_ + r0;
                vb[dt][0] = *(const bf16x8*)(vp + quad * 8);
                vb[dt][1] = *(const bf16x8*)(vp + 32 + quad * 8);
            }

            f32x4 s[2][4] = {};
            for (int st = 0; st < nst; st++) {
                #pragma unroll
                for (int qh = 0; qh < 2; qh++) {
                    s[qh][st] = __builtin_amdgcn_mfma_f32_16x16x32_bf16(kb[st][0], aq[qh][0], s[qh][st], 0,0,0);
                    s[qh][st] = __builtin_amdgcn_mfma_f32_16x16x32_bf16(kb[st][1], aq[qh][1], s[qh][st], 0,0,0);
                }
            }
            for (int st = 0; st < nst; st++) {
                bool causal = todd ? (st >= 2) : true;
                int kbq = r0 + st*16 + quad*4;
                #pragma unroll
                for (int qh = 0; qh < 2; qh++) {
                    int qg = qh ? qg1 : qg0;
                    float p0 = __builtin_amdgcn_exp2f(fmaf(s[qh][st][0], SCL, mf[st].x));
                    float p1 = __builtin_amdgcn_exp2f(fmaf(s[qh][st][1], SCL, mf[st].y));
                    float p2 = __builtin_amdgcn_exp2f(fmaf(s[qh][st][2], SCL, mf[st].z));
                    float p3 = __builtin_amdgcn_exp2f(fmaf(s[qh][st][3], SCL, mf[st].w));
                    if (causal) {
                        p0 = (kbq + 0 <= qg) ? p0 : 0.f;
                        p1 = (kbq + 1 <= qg) ? p1 : 0.f;
                        p2 = (kbq + 2 <= qg) ? p2 : 0.f;
                        p3 = (kbq + 3 <= qg) ? p3 : 0.f;
                    }
                    u32 pk0 = __builtin_amdgcn_perm(__float_as_uint(p1), __float_as_uint(p0), 0x07060302u);
                    u32 pk1 = __builtin_amdgcn_perm(__float_as_uint(p3), __float_as_uint(p2), 0x07060302u);
                    uint2 wv = {pk0, pk1};
                    *(uint2*)&Pw[(qh*16 + l15) * LDP + st*16 + quad*4] = wv;
                }
            }
            if (!todd) {
                uint2 z2 = {0u, 0u};
                #pragma unroll
                for (int st = 2; st < 4; st++)
                    #pragma unroll
                    for (int qh = 0; qh < 2; qh++)
                        *(uint2*)&Pw[(qh*16 + l15) * LDP + st*16 + quad*4] = z2;
            }
            asm volatile("s_waitcnt lgkmcnt(0)" ::: "memory");
            #pragma unroll
            for (int qh = 0; qh < 2; qh++) {
                bf16x8 ap0 = *(const bf16x8*)&Pw[(qh*16 + l15) * LDP + quad*8];
                bf16x8 ap1 = *(const bf16x8*)&Pw[(qh*16 + l15) * LDP + 32 + quad*8];
                #pragma unroll
                for (int dt = 0; dt < 4; dt++) {
                    o[qh][dt] = __builtin_amdgcn_mfma_f32_16x16x32_bf16(ap0, vb[dt][0], o[qh][dt], 0,0,0);
                    o[qh][dt] = __builtin_amdgcn_mfma_f32_16x16x32_bf16(ap1, vb[dt][1], o[qh][dt], 0,0,0);
                }
                lacc[qh] = __builtin_amdgcn_mfma_f32_16x16x32_bf16(ap0, ones, lacc[qh], 0,0,0);
                lacc[qh] = __builtin_amdgcn_mfma_f32_16x16x32_bf16(ap1, ones, lacc[qh], 0,0,0);
            }
        }

        #pragma unroll
        for (int qh = 0; qh < 2; qh++) {
            #pragma unroll
            for (int i = 0; i < 4; i++) {
                float inv = 1.f / lacc[qh][i];
                long r = tokBase + q0 + qh*16 + quad*4 + i;
                #pragma unroll
                for (int dt = 0; dt < 4; dt++)
                    O[r * D_ + h*64 + dt*16 + l15] = f2bf(o[qh][dt][i] * inv);
            }
        }
    }
}

// ------------------------------------------------- launch
extern "C" void kernel_launch(void* const* d_in, const int* in_sizes, int n_in,
                              void* d_out, int out_size, void* d_ws, size_t ws_size,
                              hipStream_t stream) {
    const float* x    = (const float*)d_in[0];
    const int*   am   = (const int*)d_in[1];
    const float* ln1a = (const float*)d_in[2];
    const float* ln1b = (const float*)d_in[3];
    const float* ln2a = (const float*)d_in[4];
    const float* ln2b = (const float*)d_in[5];
    const float* wq   = (const float*)d_in[6];
    const float* wk   = (const float*)d_in[7];
    const float* wv   = (const float*)d_in[8];
    const float* wo   = (const float*)d_in[9];
    const float* w1   = (const float*)d_in[10];
    const float* b1   = (const float*)d_in[11];
    const float* w2   = (const float*)d_in[12];
    const float* b2   = (const float*)d_in[13];
    float* out = (float*)d_out;

    // Workspace: 72 MB, liveness-overlapped 16MB slots.
    char* ws = (char*)d_ws;
    const size_t MB16 = (size_t)16 * 1024 * 1024;
    u16* y1      = (u16*)(ws + 0 * MB16);
    u16* q       = (u16*)(ws + 1 * MB16);
    u16* k       = (u16*)(ws + 2 * MB16);
    u16* v       = (u16*)(ws + 3 * MB16);
    u16* wqt     = (u16*)(ws + 4 * MB16 + 0 * (size_t)D_ * D_ * 2);
    u16* wkt     = (u16*)(ws + 4 * MB16 + 1 * (size_t)D_ * D_ * 2);
    u16* wvt     = (u16*)(ws + 4 * MB16 + 2 * (size_t)D_ * D_ * 2);
    u16* wot     = (u16*)(ws + 4 * MB16 + 3 * (size_t)D_ * D_ * 2);
    u16* y2      = y1;
    u16* w1t     = q;
    u16* w2t     = q + (size_t)D_ * DFF;
    u16* h_full  = k;
    u16* ctx     = v;
    u16*   vt  = (u16*)d_out;                                 // [0,16MB) of d_out
    float* mbias = (float*)((char*)d_out + 24 * 1024 * 1024); // 32KB; dead before x1f
    float* x1f = out;

    dim3 tb(32, 8);
    transpose_f2b4<<<dim3(D_/32, D_/32, 4), tb, 0, stream>>>(
        wq, wk, wv, wo, wqt, wkt, wvt, wot, D_, D_);

    ln_kernel<<<NT, 256, 0, stream>>>(x, ln1a, ln1b, y1);

    gemm_bt<<<dim3(D_/BN, NT/BM, 3), 256, 0, stream>>>(
        y1, wqt, wkt, wvt, q, k, v, NT, D_, D_, 0, nullptr, nullptr);

    transpose_v<<<dim3(S_/32, 2, B_*H_), tb, 0, stream>>>(v, vt);
    mask_bias_k<<<dim3(NT/256), 256, 0, stream>>>(am, mbias);

    attn_kernel<<<dim3(B_*H_, 8), 256, 0, stream>>>(q, k, vt, mbias, ctx);

    gemm_bt<<<dim3(D_/BN, NT/BM, 1), 256, 0, stream>>>(
        ctx, wot, wot, wot, x1f, x1f, x1f, NT, D_, D_, 1, nullptr, x);

    transpose_f2b<<<dim3(DFF/32, D_/32), tb, 0, stream>>>(w1, w1t, D_, DFF);
    transpose_f2b<<<dim3(D_/32, DFF/32), tb, 0, stream>>>(w2, w2t, DFF, D_);

    ln_kernel<<<NT, 256, 0, stream>>>(x1f, ln2a, ln2b, y2);

    gemm_bt<<<dim3(DFF/BN, NT/BM, 1), 256, 0, stream>>>(
        y2, w1t, w1t, w1t, h_full, h_full, h_full, NT, DFF, D_, 2, b1, nullptr);
    gemm_bt<<<dim3(D_/BN, NT/BM, 1), 256, 0, stream>>>(
        h_full, w2t, w2t, w2t, out, out, out, NT, D_, DFF, 3, b2, x1f);
}

// Round 10
// 690.516 us; speedup vs baseline: 1.1805x; 1.1268x over previous
//
#include <hip/hip_runtime.h>
#include <math.h>

typedef unsigned short u16;
typedef unsigned int u32;
typedef __attribute__((ext_vector_type(4))) unsigned short u16x4;
typedef __attribute__((ext_vector_type(8))) short bf16x8;
typedef __attribute__((ext_vector_type(4))) float f32x4;

#define B_ 4
#define S_ 2048
#define D_ 1024
#define H_ 16
#define NT (B_*S_)
#define DFF 4096

static __device__ __forceinline__ float bf2f(u16 u) {
    return __uint_as_float(((u32)u) << 16);
}
static __device__ __forceinline__ u16 f2bf(float f) {
    u32 u = __float_as_uint(f);
    u32 r = (u + 0x7fffu + ((u >> 16) & 1u)) >> 16;
    return (u16)r;
}
// async 16B/lane global->LDS (LDS dest = wave-uniform base + lane*16)
static __device__ __forceinline__ void gload_lds16(const void* g, void* l) {
    __builtin_amdgcn_global_load_lds(
        (const __attribute__((address_space(1))) void*)g,
        (__attribute__((address_space(3))) void*)l, 16, 0, 0);
}

// ------------------------------------------------- transpose fp32 -> bf16
__global__ void transpose_f2b4(const float* __restrict__ s0, const float* __restrict__ s1,
                               const float* __restrict__ s2, const float* __restrict__ s3,
                               u16* __restrict__ d0, u16* __restrict__ d1,
                               u16* __restrict__ d2, u16* __restrict__ d3,
                               int R, int C) {
    const float* in = s0; u16* out = d0;
    if (blockIdx.z == 1) { in = s1; out = d1; }
    else if (blockIdx.z == 2) { in = s2; out = d2; }
    else if (blockIdx.z == 3) { in = s3; out = d3; }
    __shared__ float t[32][33];
    int c0 = blockIdx.x * 32, r0 = blockIdx.y * 32;
    int x = threadIdx.x, y = threadIdx.y;
    #pragma unroll
    for (int i = 0; i < 4; i++)
        t[y + i*8][x] = in[(long)(r0 + y + i*8) * C + c0 + x];
    __syncthreads();
    #pragma unroll
    for (int i = 0; i < 4; i++)
        out[(long)(c0 + y + i*8) * R + r0 + x] = f2bf(t[x][y + i*8]);
}

__global__ void transpose_f2b(const float* __restrict__ in, u16* __restrict__ out,
                              int R, int C) {
    __shared__ float t[32][33];
    int c0 = blockIdx.x * 32, r0 = blockIdx.y * 32;
    int x = threadIdx.x, y = threadIdx.y;
    #pragma unroll
    for (int i = 0; i < 4; i++)
        t[y + i*8][x] = in[(long)(r0 + y + i*8) * C + c0 + x];
    __syncthreads();
    #pragma unroll
    for (int i = 0; i < 4; i++)
        out[(long)(c0 + y + i*8) * R + r0 + x] = f2bf(t[x][y + i*8]);
}

// V bf16 [B*S][D] -> Vt bf16 [B*H][64][S]. grid (S/32, 2, B*H), block (32,8)
__global__ void transpose_v(const u16* __restrict__ V, u16* __restrict__ Vt) {
    __shared__ u16 t[32][33];
    int z = blockIdx.z; int b = z >> 4, h = z & 15;
    int s0 = blockIdx.x * 32, d0 = blockIdx.y * 32;
    int x = threadIdx.x, y = threadIdx.y;
    const u16* in = V + ((long)b * S_ + s0) * D_ + h * 64 + d0;
    #pragma unroll
    for (int i = 0; i < 4; i++)
        t[y + i*8][x] = in[(long)(y + i*8) * D_ + x];
    __syncthreads();
    u16* out = Vt + ((long)z * 64 + d0) * S_ + s0;
    #pragma unroll
    for (int i = 0; i < 4; i++)
        out[(long)(y + i*8) * S_ + x] = t[x][y + i*8];
}

// ------------------------------------------------- layernorm (fp32 in, bf16 out)
__global__ __launch_bounds__(256) void ln_kernel(
    const float* __restrict__ X, const float* __restrict__ alpha,
    const float* __restrict__ beta, u16* __restrict__ Y) {
    int row = blockIdx.x, tid = threadIdx.x;
    float4 xv = ((const float4*)(X + (long)row * D_))[tid];
    float v[4] = {xv.x, xv.y, xv.z, xv.w};
    float s = 0.f, ss = 0.f;
    #pragma unroll
    for (int i = 0; i < 4; i++) { s += v[i]; ss += v[i]*v[i]; }
    #pragma unroll
    for (int off = 32; off >= 1; off >>= 1) {
        s += __shfl_xor(s, off);
        ss += __shfl_xor(ss, off);
    }
    __shared__ float red[8];
    __shared__ float stats[2];
    int w = tid >> 6;
    if ((tid & 63) == 0) { red[w] = s; red[4 + w] = ss; }
    __syncthreads();
    if (tid == 0) {
        float S = red[0] + red[1] + red[2] + red[3];
        float SS = red[4] + red[5] + red[6] + red[7];
        float mean = S * (1.f / D_);
        float var = SS * (1.f / D_) - mean * mean;
        stats[0] = mean; stats[1] = rsqrtf(var + 1e-5f);
    }
    __syncthreads();
    float mean = stats[0], rstd = stats[1];
    float4 av = ((const float4*)alpha)[tid];
    float4 bv = ((const float4*)beta)[tid];
    u16x4 o;
    o[0] = f2bf((v[0] - mean) * rstd * av.x + bv.x);
    o[1] = f2bf((v[1] - mean) * rstd * av.y + bv.y);
    o[2] = f2bf((v[2] - mean) * rstd * av.z + bv.z);
    o[3] = f2bf((v[3] - mean) * rstd * av.w + bv.w);
    *(u16x4*)(Y + (long)row * D_ + tid * 4) = o;
}

// ------------------------------------------------- GEMM (bf16 A, bf16 B^T)
// m97 recipe. launch_bounds(256,3): cap VGPR ~170 so 3 blocks/CU co-reside
// (m97 ran 164 VGPR @ 3 blocks/CU; 2-block residency was leaving staging
// stalls uncovered on QKV/W1).
#define BM 128
#define BN 128
#define BK 64

__global__ __launch_bounds__(256, 3) void gemm_bt(
    const u16* __restrict__ A,
    const u16* __restrict__ Bt0, const u16* __restrict__ Bt1, const u16* __restrict__ Bt2,
    void* __restrict__ C0, void* __restrict__ C1, void* __restrict__ C2,
    int M, int N, int K, int mode,
    const float* __restrict__ bias, const float* __restrict__ resid) {
    const u16* Bt = Bt0; void* C = C0;
    if (blockIdx.z == 1) { Bt = Bt1; C = C1; }
    else if (blockIdx.z == 2) { Bt = Bt2; C = C2; }

    __shared__ __align__(16) u16 Asm[BM * BK];
    __shared__ __align__(16) u16 Bsm[BN * BK];

    int tid = threadIdx.x;
    int lane = tid & 63, wave = tid >> 6;
    int l15 = lane & 15, quad = lane >> 4;
    int wm = wave & 1, wn = wave >> 1;
    long tm0 = (long)blockIdx.y * BM, tn0 = (long)blockIdx.x * BN;

    int srow = lane >> 3;
    int scol = (lane & 7) * 8;

    f32x4 acc[4][4] = {};

    for (int k0 = 0; k0 < K; k0 += BK) {
        __syncthreads();
        #pragma unroll
        for (int c = 0; c < 4; c++) {
            int chunk = wave * 4 + c;
            int row = chunk * 8 + srow;
            gload_lds16(&A[(tm0 + row) * (long)K + k0 + scol], &Asm[chunk * 512]);
            gload_lds16(&Bt[(tn0 + row) * (long)K + k0 + scol], &Bsm[chunk * 512]);
        }
        __syncthreads();
        #pragma unroll
        for (int ks = 0; ks < 2; ks++) {
            bf16x8 af[4], bfm[4];
            #pragma unroll
            for (int mt = 0; mt < 4; mt++)
                af[mt] = *(const bf16x8*)&Asm[(wm*64 + mt*16 + l15) * BK + ks*32 + quad*8];
            #pragma unroll
            for (int nt = 0; nt < 4; nt++)
                bfm[nt] = *(const bf16x8*)&Bsm[(wn*64 + nt*16 + l15) * BK + ks*32 + quad*8];
            #pragma unroll
            for (int mt = 0; mt < 4; mt++)
                #pragma unroll
                for (int nt = 0; nt < 4; nt++)
                    acc[mt][nt] = __builtin_amdgcn_mfma_f32_16x16x32_bf16(
                        af[mt], bfm[nt], acc[mt][nt], 0, 0, 0);
        }
    }

    #pragma unroll
    for (int mt = 0; mt < 4; mt++) {
        #pragma unroll
        for (int nt = 0; nt < 4; nt++) {
            #pragma unroll
            for (int i = 0; i < 4; i++) {
                long r = tm0 + wm*64 + mt*16 + quad*4 + i;
                long cn = tn0 + wn*64 + nt*16 + l15;
                long idx = r * N + cn;
                float val = acc[mt][nt][i];
                if (mode == 0) {
                    ((u16*)C)[idx] = f2bf(val);
                } else if (mode == 1) {
                    ((float*)C)[idx] = val + resid[idx];
                } else if (mode == 2) {
                    val += bias[cn];
                    val = 0.5f * val * (1.0f + erff(val * 0.70710678118654752f));
                    ((u16*)C)[idx] = f2bf(val);
                } else {
                    ((float*)C)[idx] = val + bias[cn] + resid[idx];
                }
            }
        }
    }
}

// ------------------------------------------------- attention (R6 verbatim)
// Wave-autonomous, ZERO barriers, fixed-max exp2 softmax, all-ones-MFMA
// denominator. Wave j = wave*8 + blockIdx.y handles q-tiles j and 63-j.
// Grid (bh=64, 8): all 8 blocks of a head land on the same XCD -> K/V stay
// in that XCD's L2 (verified R6: FETCH 146->25 MB). Measured 178 us.
// R7/R8/R9 restructurings all regressed (spills / halved intensity) — keep.
#define LDP 72   // P row stride in u16

__global__ __launch_bounds__(256, 2) void attn_kernel(
    const u16* __restrict__ Q, const u16* __restrict__ Kg, const u16* __restrict__ Vt,
    const int* __restrict__ mask, u16* __restrict__ O) {
    __shared__ __align__(16) u16 Psm[4][32 * LDP];
    int tid = threadIdx.x;
    int lane = tid & 63, wave = tid >> 6;
    int l15 = lane & 15, quad = lane >> 4;
    int bh = blockIdx.x; int b = bh >> 4, h = bh & 15;
    int j = wave * 8 + blockIdx.y;     // 0..31
    long tokBase = (long)b * S_;
    const float SCL = 0.125f * 1.4426950408889634f;  // exp2 domain
    const float MMAX = 20.0f;                        // fixed softmax shift

    const bf16x8 ones = {16256,16256,16256,16256,16256,16256,16256,16256}; // bf16 1.0
    u16* Pw = Psm[wave];
    const int* mb = mask + b * S_;

    #pragma unroll
    for (int half = 0; half < 2; half++) {
        int t = half ? (63 - j) : j;   // q-tile index 0..63
        int q0 = t * 32;

        bf16x8 aq[2][2];
        #pragma unroll
        for (int mt = 0; mt < 2; mt++) {
            const u16* qptr = Q + (tokBase + q0 + mt*16 + l15) * D_ + h * 64;
            aq[mt][0] = *(const bf16x8*)(qptr + quad * 8);
            aq[mt][1] = *(const bf16x8*)(qptr + 32 + quad * 8);
        }

        f32x4 o[2][4] = {};
        f32x4 lacc[2] = {};
        int ktiles = t / 2 + 1;

        for (int kt = 0; kt < ktiles; kt++) {
            int k0 = kt * 64;
            bf16x8 kb[4][2], vb[4][2];
            #pragma unroll
            for (int nt = 0; nt < 4; nt++) {
                const u16* kp = Kg + (tokBase + k0 + nt*16 + l15) * D_ + h * 64;
                kb[nt][0] = *(const bf16x8*)(kp + quad * 8);
                kb[nt][1] = *(const bf16x8*)(kp + 32 + quad * 8);
            }
            #pragma unroll
            for (int d = 0; d < 4; d++) {
                const u16* vp = Vt + ((long)bh * 64 + d*16 + l15) * S_ + k0;
                vb[d][0] = *(const bf16x8*)(vp + quad * 8);
                vb[d][1] = *(const bf16x8*)(vp + 32 + quad * 8);
            }

            f32x4 s[2][4] = {};
            #pragma unroll
            for (int nt = 0; nt < 4; nt++) {
                s[0][nt] = __builtin_amdgcn_mfma_f32_16x16x32_bf16(aq[0][0], kb[nt][0], s[0][nt], 0,0,0);
                s[0][nt] = __builtin_amdgcn_mfma_f32_16x16x32_bf16(aq[0][1], kb[nt][1], s[0][nt], 0,0,0);
                s[1][nt] = __builtin_amdgcn_mfma_f32_16x16x32_bf16(aq[1][0], kb[nt][0], s[1][nt], 0,0,0);
                s[1][nt] = __builtin_amdgcn_mfma_f32_16x16x32_bf16(aq[1][1], kb[nt][1], s[1][nt], 0,0,0);
            }

            int mk = 0;
            #pragma unroll
            for (int nt = 0; nt < 4; nt++)
                if (mb[k0 + nt*16 + l15] != 0) mk |= (1 << nt);

            #pragma unroll
            for (int mt = 0; mt < 2; mt++) {
                #pragma unroll
                for (int i = 0; i < 4; i++) {
                    int qq = q0 + mt*16 + quad*4 + i;
                    #pragma unroll
                    for (int nt = 0; nt < 4; nt++) {
                        int kc = k0 + nt*16 + l15;
                        float p = exp2f(fmaf(s[mt][nt][i], SCL, -MMAX));
                        p = (kc <= qq && ((mk >> nt) & 1)) ? p : 0.f;
                        Pw[(mt*16 + quad*4 + i) * LDP + nt*16 + l15] = f2bf(p);
                    }
                }
            }
            // same-wave P write -> read ordering (P is wave-private)
            asm volatile("s_waitcnt lgkmcnt(0)" ::: "memory");

            #pragma unroll
            for (int hv = 0; hv < 2; hv++) {
                bf16x8 ap0 = *(const bf16x8*)&Pw[l15 * LDP + hv*32 + quad*8];
                bf16x8 ap1 = *(const bf16x8*)&Pw[(16 + l15) * LDP + hv*32 + quad*8];
                #pragma unroll
                for (int d = 0; d < 4; d++) {
                    o[0][d] = __builtin_amdgcn_mfma_f32_16x16x32_bf16(ap0, vb[d][hv], o[0][d], 0,0,0);
                    o[1][d] = __builtin_amdgcn_mfma_f32_16x16x32_bf16(ap1, vb[d][hv], o[1][d], 0,0,0);
                }
                lacc[0] = __builtin_amdgcn_mfma_f32_16x16x32_bf16(ap0, ones, lacc[0], 0,0,0);
                lacc[1] = __builtin_amdgcn_mfma_f32_16x16x32_bf16(ap1, ones, lacc[1], 0,0,0);
            }
        }

        #pragma unroll
        for (int mt = 0; mt < 2; mt++) {
            #pragma unroll
            for (int i = 0; i < 4; i++) {
                float inv = 1.f / lacc[mt][i];
                long r = tokBase + q0 + mt*16 + quad*4 + i;
                #pragma unroll
                for (int d = 0; d < 4; d++)
                    O[r * D_ + h*64 + d*16 + l15] = f2bf(o[mt][d][i] * inv);
            }
        }
    }
}

// ------------------------------------------------- launch
extern "C" void kernel_launch(void* const* d_in, const int* in_sizes, int n_in,
                              void* d_out, int out_size, void* d_ws, size_t ws_size,
                              hipStream_t stream) {
    const float* x    = (const float*)d_in[0];
    const int*   am   = (const int*)d_in[1];
    const float* ln1a = (const float*)d_in[2];
    const float* ln1b = (const float*)d_in[3];
    const float* ln2a = (const float*)d_in[4];
    const float* ln2b = (const float*)d_in[5];
    const float* wq   = (const float*)d_in[6];
    const float* wk   = (const float*)d_in[7];
    const float* wv   = (const float*)d_in[8];
    const float* wo   = (const float*)d_in[9];
    const float* w1   = (const float*)d_in[10];
    const float* b1   = (const float*)d_in[11];
    const float* w2   = (const float*)d_in[12];
    const float* b2   = (const float*)d_in[13];
    float* out = (float*)d_out;

    // Workspace: 72 MB, liveness-overlapped 16MB slots.
    char* ws = (char*)d_ws;
    const size_t MB16 = (size_t)16 * 1024 * 1024;
    u16* y1      = (u16*)(ws + 0 * MB16);
    u16* q       = (u16*)(ws + 1 * MB16);
    u16* k       = (u16*)(ws + 2 * MB16);
    u16* v       = (u16*)(ws + 3 * MB16);
    u16* wqt     = (u16*)(ws + 4 * MB16 + 0 * (size_t)D_ * D_ * 2);
    u16* wkt     = (u16*)(ws + 4 * MB16 + 1 * (size_t)D_ * D_ * 2);
    u16* wvt     = (u16*)(ws + 4 * MB16 + 2 * (size_t)D_ * D_ * 2);
    u16* wot     = (u16*)(ws + 4 * MB16 + 3 * (size_t)D_ * D_ * 2);
    u16* y2      = y1;
    u16* w1t     = q;
    u16* w2t     = q + (size_t)D_ * DFF;
    u16* h_full  = k;
    u16* ctx     = v;
    u16*   vt  = (u16*)d_out;                // d_out scratch; dead after attn
    float* x1f = out;

    dim3 tb(32, 8);
    transpose_f2b4<<<dim3(D_/32, D_/32, 4), tb, 0, stream>>>(
        wq, wk, wv, wo, wqt, wkt, wvt, wot, D_, D_);

    ln_kernel<<<NT, 256, 0, stream>>>(x, ln1a, ln1b, y1);

    gemm_bt<<<dim3(D_/BN, NT/BM, 3), 256, 0, stream>>>(
        y1, wqt, wkt, wvt, q, k, v, NT, D_, D_, 0, nullptr, nullptr);

    transpose_v<<<dim3(S_/32, 2, B_*H_), tb, 0, stream>>>(v, vt);

    attn_kernel<<<dim3(B_*H_, 8), 256, 0, stream>>>(q, k, vt, am, ctx);

    gemm_bt<<<dim3(D_/BN, NT/BM, 1), 256, 0, stream>>>(
        ctx, wot, wot, wot, x1f, x1f, x1f, NT, D_, D_, 1, nullptr, x);

    transpose_f2b<<<dim3(DFF/32, D_/32), tb, 0, stream>>>(w1, w1t, D_, DFF);
    transpose_f2b<<<dim3(D_/32, DFF/32), tb, 0, stream>>>(w2, w2t, DFF, D_);

    ln_kernel<<<NT, 256, 0, stream>>>(x1f, ln2a, ln2b, y2);

    gemm_bt<<<dim3(DFF/BN, NT/BM, 1), 256, 0, stream>>>(
        y2, w1t, w1t, w1t, h_full, h_full, h_full, NT, DFF, D_, 2, b1, nullptr);
    gemm_bt<<<dim3(D_/BN, NT/BM, 1), 256, 0, stream>>>(
        h_full, w2t, w2t, w2t, out, out, out, NT, D_, DFF, 3, b2, x1f);
}